// Round 17
// baseline (138.767 us; speedup 1.0000x reference)
//
#include <hip/hip_runtime.h>
#include <hip/hip_bf16.h>

typedef float f32x4  __attribute__((ext_vector_type(4)));
typedef float f32x16 __attribute__((ext_vector_type(16)));
typedef short s16x8  __attribute__((ext_vector_type(8)));
typedef unsigned int u32;
typedef unsigned short u16;
typedef u16 u16x4 __attribute__((ext_vector_type(4)));
typedef u32 u32x4 __attribute__((ext_vector_type(4)));

#define DEVI static __device__ __forceinline__

constexpr int BB   = 2;
constexpr int SEQ  = 2048;
constexpr int FD   = 1024;
constexpr int NH   = 16;
constexpr int DHD  = 64;
constexpr int MROWS = BB * SEQ;

DEVI u16 f2bf(float x){
  __hip_bfloat16 h = __float2bfloat16(x);
  return __builtin_bit_cast(u16, h);
}
DEVI float bf2f(u16 u){
  return __bfloat162float(__builtin_bit_cast(__hip_bfloat16, u));
}
// HW packed f32->bf16 RNE (bit-identical to __float2bfloat16 for finite normals).
DEVI u32 cvtpk(float lo, float hi){
  u32 r;
  asm("v_cvt_pk_bf16_f32 %0, %1, %2" : "=v"(r) : "v"(lo), "v"(hi));
  return r;
}
DEVI float max3f(float a, float b, float c){
  float r;
  asm("v_max3_f32 %0, %1, %2, %3" : "=v"(r) : "v"(a), "v"(b), "v"(c));
  return r;
}

DEVI void mfma_bf16(f32x4& acc, s16x8 a, s16x8 b){
  asm("v_mfma_f32_16x16x32_bf16 %0, %1, %2, %0" : "+v"(acc) : "v"(a), "v"(b));
}
DEVI void mfma32(f32x16& acc, s16x8 a, s16x8 b){
  asm("v_mfma_f32_32x32x16_bf16 %0, %1, %2, %0" : "+v"(acc) : "v"(a), "v"(b));
}
// v_permlane32_swap_b32 vdst, vsrc: vdst.lanes[32:63] <-> vsrc.lanes[0:31].
DEVI void plswap(u32& a, u32& b){
  asm("v_permlane32_swap_b32 %0, %1" : "+v"(a), "+v"(b));
}

#define AS1C(p) ((const __attribute__((address_space(1))) void*)(p))
#define AS3(p)  ((__attribute__((address_space(3))) void*)(p))

#define VMCNT(n)  asm volatile("s_waitcnt vmcnt(" #n ")" ::: "memory")
#define LGKMCNT0  asm volatile("s_waitcnt lgkmcnt(0)" ::: "memory")
DEVI void barrier(){ __builtin_amdgcn_s_barrier(); __builtin_amdgcn_sched_barrier(0); }

// ---------------------------------------------------------------------------
// Fused prep (R9-verbatim, proven): blocks [0,6144) fp32->bf16 on q,k,v;
// blocks [6144,7168) transpose+convert the 4 weight matrices.
// ---------------------------------------------------------------------------
__global__ __launch_bounds__(256) void prep_all(
    const float* __restrict__ q, const float* __restrict__ k,
    const float* __restrict__ v, u16* __restrict__ abf,
    const float* __restrict__ W0, const float* __restrict__ W1,
    const float* __restrict__ W2, const float* __restrict__ W3,
    u16* __restrict__ T0, u16* __restrict__ T1,
    u16* __restrict__ T2, u16* __restrict__ T3)
{
  __shared__ float tile[64][65];
  const int bid = blockIdx.x;

  if (bid < 6144){
    const size_t n1 = (size_t)MROWS * FD;
    const size_t i  = ((size_t)bid * 256 + threadIdx.x) * 8;
    const float* src = (i < n1) ? q + i : (i < 2*n1 ? k + (i - n1) : v + (i - 2*n1));
    float4 v0 = *reinterpret_cast<const float4*>(src);
    float4 v1 = *reinterpret_cast<const float4*>(src + 4);
    s16x8 r;
    r[0]=(short)f2bf(v0.x); r[1]=(short)f2bf(v0.y);
    r[2]=(short)f2bf(v0.z); r[3]=(short)f2bf(v0.w);
    r[4]=(short)f2bf(v1.x); r[5]=(short)f2bf(v1.y);
    r[6]=(short)f2bf(v1.z); r[7]=(short)f2bf(v1.w);
    *reinterpret_cast<s16x8*>(abf + i) = r;
    return;
  }

  const int wb = bid - 6144;           // 0..1023
  const int z  = wb >> 8;
  const float* W = z==0?W0 : z==1?W1 : z==2?W2 : W3;
  u16* Th       = z==0?T0 : z==1?T1 : z==2?T2 : T3;

  const int kb = ((wb >> 4) & 15) * 64, nb = (wb & 15) * 64;
  const int t  = threadIdx.x;
  const int r  = t >> 2, c0 = (t & 3) * 16;

  const float* src = W + (size_t)(kb + r) * FD + nb + c0;
  #pragma unroll
  for (int i = 0; i < 16; i += 4){
    float4 vv = *reinterpret_cast<const float4*>(src + i);
    tile[r][c0+i+0] = vv.x; tile[r][c0+i+1] = vv.y;
    tile[r][c0+i+2] = vv.z; tile[r][c0+i+3] = vv.w;
  }
  __syncthreads();

  s16x8 hA, hB;
  #pragma unroll
  for (int i = 0; i < 8; i++){
    hA[i] = (short)f2bf(tile[c0 + i][r]);
    hB[i] = (short)f2bf(tile[c0 + 8 + i][r]);
  }
  const size_t o = (size_t)(nb + r) * FD + kb + c0;
  *reinterpret_cast<s16x8*>(Th + o)     = hA;
  *reinterpret_cast<s16x8*>(Th + o + 8) = hB;
}

// LDS bf16 tile, 64B rows (ogemm): chunk-XOR ((row>>1)&3), 2-way free.
DEVI s16x8 ldsT(const u16* base, int row, int g){
  const char* p = reinterpret_cast<const char*>(base);
  return *reinterpret_cast<const s16x8*>(p + (row << 6) + ((g ^ ((row >> 1) & 3)) << 4));
}
// LDS bf16 tile, 128B rows (qkv BK=64): chunk-XOR (row&7), <=2-way.
DEVI s16x8 lds64(const u16* base, int row, int chunk){
  const char* p = reinterpret_cast<const char*>(base);
  return *reinterpret_cast<const s16x8*>(p + (row << 7) + ((chunk ^ (row & 7)) << 4));
}

// ---------------------------------------------------------------------------
// Fused Q/K/V projections — R6/R11 counted-vmcnt structure, BK 32->64
// (parameter change: halves the barrier-iteration count 32->16, the measured
// cost driver). A is bf16 (prep_all), both tiles [128][64] u16, 16 KB/buffer,
// LDS 64 KB total -> 2 blocks/CU. 8 gl_lds/wave/stage -> VMCNT(8).
// Per-K-tile MFMA order = kk=0 pass then kk=1 pass == old iterations
// 2it, 2it+1 -> accumulation bit-identical to R11/R16.
// NOTE (session rule): no structural rewrites of this loop (R12/R15 class).
// ---------------------------------------------------------------------------
__global__ __launch_bounds__(256, 2) void qkv_gemm(
    const u16* __restrict__ Abase,
    const u16* __restrict__ Wq, const u16* __restrict__ Wk, const u16* __restrict__ Wv,
    const float* __restrict__ bq, const float* __restrict__ bk, const float* __restrict__ bv,
    u16* __restrict__ Q2, u16* __restrict__ K2, u16* __restrict__ Vt2)
{
  __shared__ u16 sA[2][128*64];   // 32 KB
  __shared__ u16 sW[2][128*64];   // 32 KB

  const int bid  = blockIdx.x;
  const int xcd  = bid & 7, idx = bid >> 3;          // idx 0..95
  const int strip = xcd * 12 + (idx >> 3);           // 0..95
  const int nb   = idx & 7;
  const int z    = strip >> 5, my = strip & 31;

  const u16* Ap     = Abase + (size_t)z * MROWS * FD;
  const u16*  Wh    = z==0?Wq : z==1?Wk : Wv;
  const float* bias = z==0?bq : z==1?bk : bv;
  u16* outp         = z==0?Q2 : z==1?K2 : Vt2;
  const float oscale = (z==0) ? 0.125f : 1.0f;
  const bool  tr     = (z==2);

  const int t    = threadIdx.x;
  const int nb0  = nb * 128, mb0 = my * 128;
  const int lane = t & 63, w = t >> 6;
  const int r16  = lane & 15, g = lane >> 4;
  const int wm   = (w >> 1) * 64, wn = (w & 1) * 64;

  // staging: 8 rows per issue (row&7 == lane>>3), 8x16B chunks per row,
  // source chunk pre-swizzled: (lane&7) ^ (row&7)  [both-sides rule]
  const int sRow8 = lane >> 3;           // 0..7
  const int sChk  = lane & 7;            // 0..7

  auto stage = [&](int buf, int kb){     // kb in u16 units, step 64
    #pragma unroll
    for (int i = 0; i < 4; i++){
      const int row = w*32 + i*8 + sRow8;
      const int gch = sChk ^ (row & 7);
      const u16* ag = Ap + (size_t)(mb0 + row) * FD + kb + gch*8;
      const u16* wg = Wh + (size_t)(nb0 + row) * FD + kb + gch*8;
      __builtin_amdgcn_global_load_lds(AS1C(ag), AS3(&sA[buf][(w*32 + i*8)*64]), 16, 0, 0);
      __builtin_amdgcn_global_load_lds(AS1C(wg), AS3(&sW[buf][(w*32 + i*8)*64]), 16, 0, 0);
    }
  };

  f32x4 acc[4][4] = {};

  stage(0, 0);
  stage(1, 64);
  VMCNT(8);            // buf0's 8 loads landed
  barrier();

  for (int it = 0; it < FD/64; it++){    // 16 iterations
    const int buf = it & 1;

    s16x8 a0[4], a1[4], b0[4], b1[4];
    #pragma unroll
    for (int i = 0; i < 4; i++){
      a0[i] = lds64(sA[buf], wm + i*16 + r16, g);       // K sub-tile kk=0
      a1[i] = lds64(sA[buf], wm + i*16 + r16, 4 + g);   // kk=1
    }
    #pragma unroll
    for (int j = 0; j < 4; j++){
      b0[j] = lds64(sW[buf], wn + j*16 + r16, g);
      b1[j] = lds64(sW[buf], wn + j*16 + r16, 4 + g);
    }
    LGKMCNT0;          // this wave's reads of buf retired
    barrier();         // all waves done with buf -> safe to overwrite

    if (it + 2 < FD/64) stage(buf, (it + 2) * 64);

    __builtin_amdgcn_s_setprio(1);
    #pragma unroll
    for (int i = 0; i < 4; i++)
      #pragma unroll
      for (int j = 0; j < 4; j++)
        mfma_bf16(acc[i][j], a0[i], b0[j]);   // == old iter 2it
    #pragma unroll
    for (int i = 0; i < 4; i++)
      #pragma unroll
      for (int j = 0; j < 4; j++)
        mfma_bf16(acc[i][j], a1[i], b1[j]);   // == old iter 2it+1
    __builtin_amdgcn_s_setprio(0);

    if (it + 2 < FD/64) { VMCNT(8); }   // wait only buf^1's loads (1 iter old)
    else                { VMCNT(0); }
    barrier();
  }

  #pragma unroll
  for (int i = 0; i < 4; i++){
    #pragma unroll
    for (int j = 0; j < 4; j++){
      const int ccol = nb0 + wn + j*16 + r16;
      const float bv = bias[ccol];
      #pragma unroll
      for (int r = 0; r < 4; r++){
        const int m = mb0 + wm + i*16 + g*4 + r;
        const float v = (acc[i][j][r] + bv) * oscale;
        const int b = m >> 11, n = m & (SEQ - 1);
        const int h = ccol >> 6, d = ccol & 63;
        const size_t o = tr ? ((size_t)(b*NH + h)*DHD + d)*SEQ + n
                            : ((size_t)(b*NH + h)*SEQ + n)*DHD + d;
        outp[o] = f2bf(v);
      }
    }
  }
}

// ---------------------------------------------------------------------------
// O-projection GEMM, counted-vmcnt template (R16-exact, frozen).
// ---------------------------------------------------------------------------
__global__ __launch_bounds__(256, 3) void ogemm_k(
    const u16* __restrict__ Ap, const u16* __restrict__ Wh,
    const float* __restrict__ bias, float* __restrict__ outp)
{
  __shared__ u16 sA[2][64*32];
  __shared__ u16 sW[2][128*32];

  const int bid  = blockIdx.x;
  const int xcd  = bid & 7, idx = bid >> 3;
  const int my   = xcd * 8 + (idx >> 3);
  const int nb   = idx & 7;

  const int t    = threadIdx.x;
  const int nb0  = nb * 128, mb0 = my * 64;
  const int lane = t & 63, w = t >> 6;
  const int r16  = lane & 15, g = lane >> 4;
  const int wm   = (w >> 1) * 32, wn = (w & 1) * 64;

  const int sRow   = lane >> 2;
  const int sChunk = (lane & 3);

  auto stage = [&](int buf, int kb){
    {
      const int row = w*16 + sRow;
      const int gch = sChunk ^ ((row >> 1) & 3);
      const u16* ag = Ap + (size_t)(mb0 + row) * FD + kb + gch*8;
      __builtin_amdgcn_global_load_lds(AS1C(ag), AS3(&sA[buf][(w*16)*32]), 16, 0, 0);
    }
    #pragma unroll
    for (int i = 0; i < 2; i++){
      const int row = w*32 + i*16 + sRow;
      const int gch = sChunk ^ ((row >> 1) & 3);
      const u16* wg = Wh + (size_t)(nb0 + row) * FD + kb + gch*8;
      __builtin_amdgcn_global_load_lds(AS1C(wg), AS3(&sW[buf][(w*32 + i*16)*32]), 16, 0, 0);
    }
  };

  f32x4 acc[2][4] = {};

  stage(0, 0);
  stage(1, 32);
  VMCNT(3);
  barrier();

  #pragma unroll 2
  for (int it = 0; it < FD/32; it++){
    const int buf = it & 1;

    s16x8 a[2], bh[4];
    #pragma unroll
    for (int i = 0; i < 2; i++)
      a[i]  = ldsT(sA[buf], wm + i*16 + r16, g);
    #pragma unroll
    for (int j = 0; j < 4; j++)
      bh[j] = ldsT(sW[buf], wn + j*16 + r16, g);
    LGKMCNT0;
    barrier();

    if (it + 2 < FD/32) stage(buf, (it + 2) * 32);

    __builtin_amdgcn_s_setprio(1);
    #pragma unroll
    for (int i = 0; i < 2; i++)
      #pragma unroll
      for (int j = 0; j < 4; j++)
        mfma_bf16(acc[i][j], a[i], bh[j]);
    __builtin_amdgcn_s_setprio(0);

    if (it + 2 < FD/32) { VMCNT(3); }
    else                { VMCNT(0); }
    barrier();
  }

  #pragma unroll
  for (int i = 0; i < 2; i++){
    #pragma unroll
    for (int j = 0; j < 4; j++){
      const int ccol = nb0 + wn + j*16 + r16;
      const float bv = bias[ccol];
      #pragma unroll
      for (int r = 0; r < 4; r++){
        const int m = mb0 + wm + i*16 + g*4 + r;
        outp[(size_t)m * FD + ccol] = acc[i][j][r] + bv;
      }
    }
  }
}

// ---------------------------------------------------------------------------
// Flash attention — R11-exact body (passing). FROZEN.
// Maxless (R7/R8), pipelined (R12), and other inner-loop rewrites fail
// ~1e-2 in this toolchain; do not restructure.
// ---------------------------------------------------------------------------
__global__ __launch_bounds__(512, 4) void attn_k(
    const u16* __restrict__ Q2, const u16* __restrict__ K2, const u16* __restrict__ Vt2,
    u16* __restrict__ AOh)
{
  __shared__ u16 smem[2][2][2][64*64];

  const int bid = blockIdx.x + 16 * blockIdx.y;
  const int qt  = bid >> 5;
  const int bh  = (bid & 7) * 4 + ((bid >> 3) & 3);

  const int t = threadIdx.x, w = t >> 6, lane = t & 63;
  const int grp = w >> 2, gw = w & 3;
  const int l31 = lane & 31, hi = lane >> 5;

  const u16* Kb = K2  + (size_t)bh * SEQ * DHD;
  const u16* Vb = Vt2 + (size_t)bh * DHD * SEQ;

  const int srow8  = lane >> 3;
  const int schunk = ((lane & 7) ^ srow8) * 8;

  const int qrow = qt*128 + gw*32 + l31;
  const u16* Qrow = Q2 + ((size_t)bh * SEQ + qrow) * DHD;
  s16x8 qf[4];
  #pragma unroll
  for (int dk = 0; dk < 4; dk++)
    qf[dk] = *reinterpret_cast<const s16x8*>(Qrow + dk*16 + hi*8);

  f32x16 ot0 = {}, ot1 = {};
  float mrun = -1e30f, lrun = 0.f;

  auto stage_tile = [&](int buf, int kt){
    #pragma unroll
    for (int i = 0; i < 2; i++){
      const int row = gw*16 + i*8 + srow8;
      const u16* kg = Kb + (size_t)(kt*64 + row) * DHD + schunk;
      const u16* vg = Vb + (size_t)row * SEQ + kt*64 + schunk;
      __builtin_amdgcn_global_load_lds(AS1C(kg), AS3(&smem[0][grp][buf][(gw*16 + i*8)*64]), 16, 0, 0);
      __builtin_amdgcn_global_load_lds(AS1C(vg), AS3(&smem[1][grp][buf][(gw*16 + i*8)*64]), 16, 0, 0);
    }
  };
  auto lds16 = [](const u16* base, int row, int colbyte) -> s16x8 {
    int off = (row << 7) + colbyte;
    off ^= (row & 7) << 4;
    return *reinterpret_cast<const s16x8*>(reinterpret_cast<const char*>(base) + off);
  };

  constexpr int NIT = SEQ / 64 / 2;
  stage_tile(0, grp);
  __syncthreads();

  for (int i = 0; i < NIT; i++){
    const int buf = i & 1;
    if (i + 1 < NIT) stage_tile(buf ^ 1, 2*(i+1) + grp);
    const u16* sK = &smem[0][grp][buf][0];
    const u16* sV = &smem[1][grp][buf][0];

    f32x16 st0 = {}, st1 = {};
    __builtin_amdgcn_s_setprio(1);
    #pragma unroll
    for (int dk = 0; dk < 4; dk++){
      s16x8 kf0 = lds16(sK, l31,      dk*32 + hi*16);
      s16x8 kf1 = lds16(sK, 32 + l31, dk*32 + hi*16);
      mfma32(st0, kf0, qf[dk]);
      mfma32(st1, kf1, qf[dk]);
    }
    __builtin_amdgcn_s_setprio(0);

    float a0 = max3f(st0[0],  st0[1],  st0[2]);
    float a1 = max3f(st0[3],  st0[4],  st0[5]);
    float a2 = max3f(st0[6],  st0[7],  st0[8]);
    float a3 = max3f(st0[9],  st0[10], st0[11]);
    float a4 = max3f(st0[12], st0[13], st0[14]);
    float a5 = max3f(st1[0],  st1[1],  st1[2]);
    float a6 = max3f(st1[3],  st1[4],  st1[5]);
    float a7 = max3f(st1[6],  st1[7],  st1[8]);
    float a8 = max3f(st1[9],  st1[10], st1[11]);
    float a9 = max3f(st1[12], st1[13], st1[14]);
    float b0 = max3f(a0, a1, a2);
    float b1 = max3f(a3, a4, a5);
    float b2 = max3f(a6, a7, a8);
    float b3 = max3f(a9, st0[15], st1[15]);
    float pmax = fmaxf(max3f(b0, b1, b2), b3);
    pmax = fmaxf(pmax, __shfl_xor(pmax, 32, 64));

    if (!__all(pmax <= mrun + 8.f)){      // defer-max (T13)
      float mnew = fmaxf(mrun, pmax);
      float alp = __expf(mrun - mnew);
      mrun = mnew;
      lrun *= alp;
      #pragma unroll
      for (int r = 0; r < 16; r++){ ot0[r] *= alp; ot1[r] *= alp; }
    }

    #pragma unroll
    for (int r = 0; r < 16; r++){
      st0[r] = __expf(st0[r] - mrun);
      st1[r] = __expf(st1[r] - mrun);
    }
    float s8[8];
    #pragma unroll
    for (int r = 0; r < 8; r++)
      s8[r] = (st0[r] + st0[r+8]) + (st1[r] + st1[r+8]);
    float psum = ((s8[0]+s8[1])+(s8[2]+s8[3])) + ((s8[4]+s8[5])+(s8[6]+s8[7]));
    psum += __shfl_xor(psum, 32, 64);
    lrun += psum;

    u32 pw[16];
    #pragma unroll
    for (int g2 = 0; g2 < 4; g2++){
      pw[g2*2+0]   = cvtpk(st0[g2*4+0], st0[g2*4+1]);
      pw[g2*2+1]   = cvtpk(st0[g2*4+2], st0[g2*4+3]);
      pw[8+g2*2+0] = cvtpk(st1[g2*4+0], st1[g2*4+1]);
      pw[8+g2*2+1] = cvtpk(st1[g2*4+2], st1[g2*4+3]);
    }
    s16x8 pb[4];
    #pragma unroll
    for (int ks = 0; ks < 4; ks++){
      const int e = (ks>>1)*8 + (ks&1)*4;
      u32 w0 = pw[e+0], w1 = pw[e+1], w2 = pw[e+2], w3 = pw[e+3];
      plswap(w0, w2);
      plswap(w1, w3);
      u32x4 wv = { w0, w1, w2, w3 };
      pb[ks] = __builtin_bit_cast(s16x8, wv);
    }

    __builtin_amdgcn_s_setprio(1);
    #pragma unroll
    for (int ks = 0; ks < 4; ks++){
      s16x8 vf0 = lds16(sV, l31,      ks*32 + hi*16);
      s16x8 vf1 = lds16(sV, 32 + l31, ks*32 + hi*16);
      mfma32(ot0, vf0, pb[ks]);
      mfma32(ot1, vf1, pb[ks]);
    }
    __builtin_amdgcn_s_setprio(0);

    __syncthreads();
  }

  float* sO = reinterpret_cast<float*>(&smem[0][0][0][0]);
  float* sM = reinterpret_cast<float*>(&smem[0][0][0][0]) + 128*68;
  const int ql = gw*32 + l31;

  if (grp == 1){
    #pragma unroll
    for (int r4 = 0; r4 < 4; r4++){
      const int d0 = r4*8 + hi*4;
      #pragma unroll
      for (int j = 0; j < 4; j++){
        sO[ql*68 + d0 + j]      = ot0[r4*4+j];
        sO[ql*68 + 32 + d0 + j] = ot1[r4*4+j];
      }
    }
    if (hi == 0){ sM[ql*2+0] = mrun; sM[ql*2+1] = lrun; }
  }
  __syncthreads();
  if (grp == 0){
    const float m1 = sM[ql*2+0], l1 = sM[ql*2+1];
    const float M  = fmaxf(mrun, m1);
    const float w0 = __expf(mrun - M), w1e = __expf(m1 - M);
    const float inv = 1.0f / (lrun*w0 + l1*w1e);

    const int b = bh >> 4, h = bh & 15;
    u16* orow = AOh + ((size_t)b*SEQ + qrow) * FD + h*64;
    #pragma unroll
    for (int r4 = 0; r4 < 4; r4++){
      const int d0 = r4*8 + hi*4;
      u16x4 v0, v1;
      #pragma unroll
      for (int j = 0; j < 4; j++){
        v0[j] = f2bf((ot0[r4*4+j]*w0 + sO[ql*68 + d0 + j]*w1e) * inv);
        v1[j] = f2bf((ot1[r4*4+j]*w0 + sO[ql*68 + 32 + d0 + j]*w1e) * inv);
      }
      *reinterpret_cast<u16x4*>(orow + d0)      = v0;
      *reinterpret_cast<u16x4*>(orow + 32 + d0) = v1;
    }
  }
}

// ---------------------------------------------------------------------------
extern "C" void kernel_launch(void* const* d_in, const int* in_sizes, int n_in,
                              void* d_out, int out_size, void* d_ws, size_t ws_size,
                              hipStream_t stream)
{
  const float* q  = (const float*)d_in[0];
  const float* k  = (const float*)d_in[1];
  const float* v  = (const float*)d_in[2];
  const float* Wq = (const float*)d_in[3];
  const float* bq = (const float*)d_in[4];
  const float* Wk = (const float*)d_in[5];
  const float* bk = (const float*)d_in[6];
  const float* Wv = (const float*)d_in[7];
  const float* bv = (const float*)d_in[8];
  const float* Wo = (const float*)d_in[9];
  const float* bo = (const float*)d_in[10];
  float* out = (float*)d_out;
  (void)in_sizes; (void)n_in; (void)out_size; (void)ws_size;

  char* ws = (char*)d_ws;
  size_t off = 0;
  auto alloc = [&](size_t bytes) -> char* {
    char* p = ws + off;
    off += (bytes + 255) & ~(size_t)255;
    return p;
  };
  const size_t WB = (size_t)FD * FD * sizeof(u16);             // 2 MB
  u16* WqTh = (u16*)alloc(WB);
  u16* WkTh = (u16*)alloc(WB);
  u16* WvTh = (u16*)alloc(WB);
  u16* WoTh = (u16*)alloc(WB);
  const size_t QB = (size_t)BB * NH * SEQ * DHD * sizeof(u16); // 8 MB
  u16* Q2  = (u16*)alloc(QB);
  u16* K2  = (u16*)alloc(QB);
  u16* Vt2 = (u16*)alloc(QB);
  const size_t AB = (size_t)BB * SEQ * FD * sizeof(u16);       // 8 MB
  u16* AOh = (u16*)alloc(AB);
  u16* Abf = (u16*)alloc(3 * AB);                              // 24 MB bf16 q,k,v

  prep_all<<<dim3(7168), 256, 0, stream>>>(q, k, v, Abf,
                                           Wq, Wk, Wv, Wo,
                                           WqTh, WkTh, WvTh, WoTh);

  qkv_gemm<<<dim3(768), 256, 0, stream>>>(Abf, WqTh, WkTh, WvTh,
                                          bq, bk, bv, Q2, K2, Vt2);

  attn_k<<<dim3(16,32), 512, 0, stream>>>(Q2, K2, Vt2, AOh);

  ogemm_k<<<dim3(512), 256, 0, stream>>>(AOh, WoTh, bo, out);
}

// Round 18
// 136.704 us; speedup vs baseline: 1.0151x; 1.0151x over previous
//
#include <hip/hip_runtime.h>
#include <hip/hip_bf16.h>

typedef float f32x4  __attribute__((ext_vector_type(4)));
typedef float f32x16 __attribute__((ext_vector_type(16)));
typedef short s16x8  __attribute__((ext_vector_type(8)));
typedef unsigned int u32;
typedef unsigned short u16;
typedef u16 u16x4 __attribute__((ext_vector_type(4)));
typedef u32 u32x4 __attribute__((ext_vector_type(4)));

#define DEVI static __device__ __forceinline__

constexpr int BB   = 2;
constexpr int SEQ  = 2048;
constexpr int FD   = 1024;
constexpr int NH   = 16;
constexpr int DHD  = 64;
constexpr int MROWS = BB * SEQ;

DEVI u16 f2bf(float x){
  __hip_bfloat16 h = __float2bfloat16(x);
  return __builtin_bit_cast(u16, h);
}
DEVI float bf2f(u16 u){
  return __bfloat162float(__builtin_bit_cast(__hip_bfloat16, u));
}
// HW packed f32->bf16 RNE (bit-identical to __float2bfloat16 for finite normals).
DEVI u32 cvtpk(float lo, float hi){
  u32 r;
  asm("v_cvt_pk_bf16_f32 %0, %1, %2" : "=v"(r) : "v"(lo), "v"(hi));
  return r;
}
DEVI float max3f(float a, float b, float c){
  float r;
  asm("v_max3_f32 %0, %1, %2, %3" : "=v"(r) : "v"(a), "v"(b), "v"(c));
  return r;
}

DEVI void mfma_bf16(f32x4& acc, s16x8 a, s16x8 b){
  asm("v_mfma_f32_16x16x32_bf16 %0, %1, %2, %0" : "+v"(acc) : "v"(a), "v"(b));
}
DEVI void mfma32(f32x16& acc, s16x8 a, s16x8 b){
  asm("v_mfma_f32_32x32x16_bf16 %0, %1, %2, %0" : "+v"(acc) : "v"(a), "v"(b));
}
// v_permlane32_swap_b32 vdst, vsrc: vdst.lanes[32:63] <-> vsrc.lanes[0:31].
DEVI void plswap(u32& a, u32& b){
  asm("v_permlane32_swap_b32 %0, %1" : "+v"(a), "+v"(b));
}

#define AS1C(p) ((const __attribute__((address_space(1))) void*)(p))
#define AS3(p)  ((__attribute__((address_space(3))) void*)(p))

#define VMCNT(n)  asm volatile("s_waitcnt vmcnt(" #n ")" ::: "memory")
#define LGKMCNT0  asm volatile("s_waitcnt lgkmcnt(0)" ::: "memory")
DEVI void barrier(){ __builtin_amdgcn_s_barrier(); __builtin_amdgcn_sched_barrier(0); }

// ---------------------------------------------------------------------------
// Weight prep: W[k][n] fp32 -> WT[n][k] bf16. (R16-exact, frozen.)
// ---------------------------------------------------------------------------
__global__ __launch_bounds__(256) void wprep_all(
    const float* __restrict__ W0, const float* __restrict__ W1,
    const float* __restrict__ W2, const float* __restrict__ W3,
    u16* __restrict__ T0, u16* __restrict__ T1,
    u16* __restrict__ T2, u16* __restrict__ T3)
{
  const int z = blockIdx.z;
  const float* W = z==0?W0 : z==1?W1 : z==2?W2 : W3;
  u16* Th       = z==0?T0 : z==1?T1 : z==2?T2 : T3;

  __shared__ float tile[64][65];
  const int kb = blockIdx.x * 64, nb = blockIdx.y * 64;
  const int t  = threadIdx.x;
  const int r  = t >> 2, c0 = (t & 3) * 16;

  const float* src = W + (size_t)(kb + r) * FD + nb + c0;
  #pragma unroll
  for (int i = 0; i < 16; i += 4){
    float4 v = *reinterpret_cast<const float4*>(src + i);
    tile[r][c0+i+0] = v.x; tile[r][c0+i+1] = v.y;
    tile[r][c0+i+2] = v.z; tile[r][c0+i+3] = v.w;
  }
  __syncthreads();

  s16x8 hA, hB;
  #pragma unroll
  for (int i = 0; i < 8; i++){
    hA[i] = (short)f2bf(tile[c0 + i][r]);
    hB[i] = (short)f2bf(tile[c0 + 8 + i][r]);
  }
  const size_t o = (size_t)(nb + r) * FD + kb + c0;
  *reinterpret_cast<s16x8*>(Th + o)     = hA;
  *reinterpret_cast<s16x8*>(Th + o + 8) = hB;
}

// LDS bf16 tile, 64B rows (qkv W): chunk-XOR ((row>>1)&3), 2-way free.
DEVI s16x8 ldsT(const u16* base, int row, int g){
  const char* p = reinterpret_cast<const char*>(base);
  return *reinterpret_cast<const s16x8*>(p + (row << 6) + ((g ^ ((row >> 1) & 3)) << 4));
}
// LDS bf16 tile, 128B rows (ogemm BK=64): chunk-XOR (row&7).
DEVI s16x8 lds64(const u16* base, int row, int chunk){
  const char* p = reinterpret_cast<const char*>(base);
  return *reinterpret_cast<const s16x8*>(p + (row << 7) + ((chunk ^ (row & 7)) << 4));
}

// ---------------------------------------------------------------------------
// Fused Q/K/V projections — R16-exact (best measured: total 136.2).
// fp32 A staged directly via global_load_lds, cvtpk at fragment read.
// NOTE (session rule): no structural rewrites (R12/R15 class failed ~1e-2).
// ---------------------------------------------------------------------------
__global__ __launch_bounds__(256, 3) void qkv_gemm(
    const float* __restrict__ qp, const float* __restrict__ kp, const float* __restrict__ vp,
    const u16* __restrict__ Wq, const u16* __restrict__ Wk, const u16* __restrict__ Wv,
    const float* __restrict__ bq, const float* __restrict__ bk, const float* __restrict__ bv,
    u16* __restrict__ Q2, u16* __restrict__ K2, u16* __restrict__ Vt2)
{
  __shared__ float sAf[2][128*32];   // fp32 A tile, 128 B rows (32 KB)
  __shared__ u16   sW [2][128*32];   // bf16 W tile, 64 B rows (16 KB)

  const int bid  = blockIdx.x;
  const int xcd  = bid & 7, idx = bid >> 3;          // idx 0..95
  const int strip = xcd * 12 + (idx >> 3);           // 0..95
  const int nb   = idx & 7;
  const int z    = strip >> 5, my = strip & 31;

  const float* Ap   = z==0?qp : z==1?kp : vp;
  const u16*  Wh    = z==0?Wq : z==1?Wk : Wv;
  const float* bias = z==0?bq : z==1?bk : bv;
  u16* outp         = z==0?Q2 : z==1?K2 : Vt2;
  const float oscale = (z==0) ? 0.125f : 1.0f;
  const bool  tr     = (z==2);

  const int t    = threadIdx.x;
  const int nb0  = nb * 128, mb0 = my * 128;
  const int lane = t & 63, w = t >> 6;
  const int r16  = lane & 15, g = lane >> 4;
  const int wm   = (w >> 1) * 64, wn = (w & 1) * 64;

  const int aRow   = lane >> 3;                      // 0..7
  const int aChunk = ((lane & 7) ^ aRow) * 4;        // float offset of 16B chunk
  const int sRow   = lane >> 2;                      // 0..15
  const int sChunk = (lane & 3);

  auto stage = [&](int buf, int kb){
    #pragma unroll
    for (int i = 0; i < 4; i++){                     // A: 4 issues x 8 rows
      const int row = w*32 + i*8 + aRow;
      const float* ag = Ap + (size_t)(mb0 + row) * FD + kb + aChunk;
      __builtin_amdgcn_global_load_lds(AS1C(ag), AS3(&sAf[buf][(w*32 + i*8)*32]), 16, 0, 0);
    }
    #pragma unroll
    for (int i = 0; i < 2; i++){                     // W: 2 issues x 16 rows
      const int row = w*32 + i*16 + sRow;
      const int gch = sChunk ^ ((row >> 1) & 3);
      const u16* wg = Wh + (size_t)(nb0 + row) * FD + kb + gch*8;
      __builtin_amdgcn_global_load_lds(AS1C(wg), AS3(&sW[buf][(w*32 + i*16)*32]), 16, 0, 0);
    }
  };
  auto ldsA = [&](const float* base, int row, int gg) -> s16x8 {
    const char* p = reinterpret_cast<const char*>(base);
    const int roff = row << 7, sw = (row & 7) << 4;
    f32x4 lo = *reinterpret_cast<const f32x4*>(p + roff + ((gg*32)      ^ sw));
    f32x4 hi = *reinterpret_cast<const f32x4*>(p + roff + ((gg*32 + 16) ^ sw));
    u32 w0 = cvtpk(lo[0], lo[1]);
    u32 w1 = cvtpk(lo[2], lo[3]);
    u32 w2 = cvtpk(hi[0], hi[1]);
    u32 w3 = cvtpk(hi[2], hi[3]);
    u32x4 wv = { w0, w1, w2, w3 };
    return __builtin_bit_cast(s16x8, wv);
  };

  f32x4 acc[4][4] = {};

  stage(0, 0);
  stage(1, 32);
  VMCNT(6);            // buf0's 6 loads landed
  barrier();

  #pragma unroll 2
  for (int it = 0; it < FD/32; it++){
    const int buf = it & 1;

    s16x8 a[4], bh[4];
    #pragma unroll
    for (int i = 0; i < 4; i++)
      a[i]  = ldsA(sAf[buf], wm + i*16 + r16, g);
    #pragma unroll
    for (int j = 0; j < 4; j++)
      bh[j] = ldsT(sW[buf], wn + j*16 + r16, g);
    LGKMCNT0;          // this wave's reads of buf retired
    barrier();         // ALL waves done with buf -> safe to overwrite

    if (it + 2 < FD/32) stage(buf, (it + 2) * 32);

    __builtin_amdgcn_s_setprio(1);
    #pragma unroll
    for (int i = 0; i < 4; i++)
      #pragma unroll
      for (int j = 0; j < 4; j++)
        mfma_bf16(acc[i][j], a[i], bh[j]);
    __builtin_amdgcn_s_setprio(0);

    if (it + 2 < FD/32) { VMCNT(6); }   // wait only buf^1's loads (1 iter old)
    else                { VMCNT(0); }
    barrier();
  }

  #pragma unroll
  for (int i = 0; i < 4; i++){
    #pragma unroll
    for (int j = 0; j < 4; j++){
      const int ccol = nb0 + wn + j*16 + r16;
      const float bv = bias[ccol];
      #pragma unroll
      for (int r = 0; r < 4; r++){
        const int m = mb0 + wm + i*16 + g*4 + r;
        const float v = (acc[i][j][r] + bv) * oscale;
        const int b = m >> 11, n = m & (SEQ - 1);
        const int h = ccol >> 6, d = ccol & 63;
        const size_t o = tr ? ((size_t)(b*NH + h)*DHD + d)*SEQ + n
                            : ((size_t)(b*NH + h)*SEQ + n)*DHD + d;
        outp[o] = f2bf(v);
      }
    }
  }
}

// ---------------------------------------------------------------------------
// O-projection GEMM — BK 32->64 (R17-proven parameter class): halves the
// barrier-iteration count 32->16 at unchanged LDS total (48 KB, 3 blocks/CU).
// Both operands already bf16 (AOh, WoTh) so no prep needed. Per-K-tile MFMA
// order = kk=0 pass then kk=1 == old iterations 2it, 2it+1 -> bit-identical.
// Staging 6 gl_lds/wave (A:2 + W:4, 8-row issues, chunk-XOR (row&7)).
// ---------------------------------------------------------------------------
__global__ __launch_bounds__(256, 3) void ogemm_k(
    const u16* __restrict__ Ap, const u16* __restrict__ Wh,
    const float* __restrict__ bias, float* __restrict__ outp)
{
  __shared__ u16 sA[2][64*64];    // 16 KB
  __shared__ u16 sW[2][128*64];   // 32 KB

  const int bid  = blockIdx.x;
  const int xcd  = bid & 7, idx = bid >> 3;
  const int my   = xcd * 8 + (idx >> 3);
  const int nb   = idx & 7;

  const int t    = threadIdx.x;
  const int nb0  = nb * 128, mb0 = my * 64;
  const int lane = t & 63, w = t >> 6;
  const int r16  = lane & 15, g = lane >> 4;
  const int wm   = (w >> 1) * 32, wn = (w & 1) * 64;

  const int sRow8 = lane >> 3;           // 0..7
  const int sChk  = lane & 7;            // 0..7

  auto stage = [&](int buf, int kb){     // kb in u16 units, step 64
    #pragma unroll
    for (int i = 0; i < 2; i++){         // A: 2 issues x 8 rows (64 rows total)
      const int row = w*16 + i*8 + sRow8;
      const int gch = sChk ^ (row & 7);
      const u16* ag = Ap + (size_t)(mb0 + row) * FD + kb + gch*8;
      __builtin_amdgcn_global_load_lds(AS1C(ag), AS3(&sA[buf][(w*16 + i*8)*64]), 16, 0, 0);
    }
    #pragma unroll
    for (int i = 0; i < 4; i++){         // W: 4 issues x 8 rows (128 rows)
      const int row = w*32 + i*8 + sRow8;
      const int gch = sChk ^ (row & 7);
      const u16* wg = Wh + (size_t)(nb0 + row) * FD + kb + gch*8;
      __builtin_amdgcn_global_load_lds(AS1C(wg), AS3(&sW[buf][(w*32 + i*8)*64]), 16, 0, 0);
    }
  };

  f32x4 acc[2][4] = {};

  stage(0, 0);
  stage(1, 64);
  VMCNT(6);            // buf0's 6 loads landed
  barrier();

  for (int it = 0; it < FD/64; it++){    // 16 iterations
    const int buf = it & 1;

    s16x8 a0[2], a1[2], b0[4], b1[4];
    #pragma unroll
    for (int i = 0; i < 2; i++){
      a0[i] = lds64(sA[buf], wm + i*16 + r16, g);       // kk=0
      a1[i] = lds64(sA[buf], wm + i*16 + r16, 4 + g);   // kk=1
    }
    #pragma unroll
    for (int j = 0; j < 4; j++){
      b0[j] = lds64(sW[buf], wn + j*16 + r16, g);
      b1[j] = lds64(sW[buf], wn + j*16 + r16, 4 + g);
    }
    LGKMCNT0;
    barrier();

    if (it + 2 < FD/64) stage(buf, (it + 2) * 64);

    __builtin_amdgcn_s_setprio(1);
    #pragma unroll
    for (int i = 0; i < 2; i++)
      #pragma unroll
      for (int j = 0; j < 4; j++)
        mfma_bf16(acc[i][j], a0[i], b0[j]);   // == old iter 2it
    #pragma unroll
    for (int i = 0; i < 2; i++)
      #pragma unroll
      for (int j = 0; j < 4; j++)
        mfma_bf16(acc[i][j], a1[i], b1[j]);   // == old iter 2it+1
    __builtin_amdgcn_s_setprio(0);

    if (it + 2 < FD/64) { VMCNT(6); }
    else                { VMCNT(0); }
    barrier();
  }

  #pragma unroll
  for (int i = 0; i < 2; i++){
    #pragma unroll
    for (int j = 0; j < 4; j++){
      const int ccol = nb0 + wn + j*16 + r16;
      const float bv = bias[ccol];
      #pragma unroll
      for (int r = 0; r < 4; r++){
        const int m = mb0 + wm + i*16 + g*4 + r;
        outp[(size_t)m * FD + ccol] = acc[i][j][r] + bv;
      }
    }
  }
}

// ---------------------------------------------------------------------------
// Flash attention — R11-exact body (passing). FROZEN.
// Maxless (R7/R8), pipelined (R12), and other inner-loop rewrites fail
// ~1e-2 in this toolchain; do not restructure.
// ---------------------------------------------------------------------------
__global__ __launch_bounds__(512, 4) void attn_k(
    const u16* __restrict__ Q2, const u16* __restrict__ K2, const u16* __restrict__ Vt2,
    u16* __restrict__ AOh)
{
  __shared__ u16 smem[2][2][2][64*64];

  const int bid = blockIdx.x + 16 * blockIdx.y;
  const int qt  = bid >> 5;
  const int bh  = (bid & 7) * 4 + ((bid >> 3) & 3);

  const int t = threadIdx.x, w = t >> 6, lane = t & 63;
  const int grp = w >> 2, gw = w & 3;
  const int l31 = lane & 31, hi = lane >> 5;

  const u16* Kb = K2  + (size_t)bh * SEQ * DHD;
  const u16* Vb = Vt2 + (size_t)bh * DHD * SEQ;

  const int srow8  = lane >> 3;
  const int schunk = ((lane & 7) ^ srow8) * 8;

  const int qrow = qt*128 + gw*32 + l31;
  const u16* Qrow = Q2 + ((size_t)bh * SEQ + qrow) * DHD;
  s16x8 qf[4];
  #pragma unroll
  for (int dk = 0; dk < 4; dk++)
    qf[dk] = *reinterpret_cast<const s16x8*>(Qrow + dk*16 + hi*8);

  f32x16 ot0 = {}, ot1 = {};
  float mrun = -1e30f, lrun = 0.f;

  auto stage_tile = [&](int buf, int kt){
    #pragma unroll
    for (int i = 0; i < 2; i++){
      const int row = gw*16 + i*8 + srow8;
      const u16* kg = Kb + (size_t)(kt*64 + row) * DHD + schunk;
      const u16* vg = Vb + (size_t)row * SEQ + kt*64 + schunk;
      __builtin_amdgcn_global_load_lds(AS1C(kg), AS3(&smem[0][grp][buf][(gw*16 + i*8)*64]), 16, 0, 0);
      __builtin_amdgcn_global_load_lds(AS1C(vg), AS3(&smem[1][grp][buf][(gw*16 + i*8)*64]), 16, 0, 0);
    }
  };
  auto lds16 = [](const u16* base, int row, int colbyte) -> s16x8 {
    int off = (row << 7) + colbyte;
    off ^= (row & 7) << 4;
    return *reinterpret_cast<const s16x8*>(reinterpret_cast<const char*>(base) + off);
  };

  constexpr int NIT = SEQ / 64 / 2;
  stage_tile(0, grp);
  __syncthreads();

  for (int i = 0; i < NIT; i++){
    const int buf = i & 1;
    if (i + 1 < NIT) stage_tile(buf ^ 1, 2*(i+1) + grp);
    const u16* sK = &smem[0][grp][buf][0];
    const u16* sV = &smem[1][grp][buf][0];

    f32x16 st0 = {}, st1 = {};
    __builtin_amdgcn_s_setprio(1);
    #pragma unroll
    for (int dk = 0; dk < 4; dk++){
      s16x8 kf0 = lds16(sK, l31,      dk*32 + hi*16);
      s16x8 kf1 = lds16(sK, 32 + l31, dk*32 + hi*16);
      mfma32(st0, kf0, qf[dk]);
      mfma32(st1, kf1, qf[dk]);
    }
    __builtin_amdgcn_s_setprio(0);

    float a0 = max3f(st0[0],  st0[1],  st0[2]);
    float a1 = max3f(st0[3],  st0[4],  st0[5]);
    float a2 = max3f(st0[6],  st0[7],  st0[8]);
    float a3 = max3f(st0[9],  st0[10], st0[11]);
    float a4 = max3f(st0[12], st0[13], st0[14]);
    float a5 = max3f(st1[0],  st1[1],  st1[2]);
    float a6 = max3f(st1[3],  st1[4],  st1[5]);
    float a7 = max3f(st1[6],  st1[7],  st1[8]);
    float a8 = max3f(st1[9],  st1[10], st1[11]);
    float a9 = max3f(st1[12], st1[13], st1[14]);
    float b0 = max3f(a0, a1, a2);
    float b1 = max3f(a3, a4, a5);
    float b2 = max3f(a6, a7, a8);
    float b3 = max3f(a9, st0[15], st1[15]);
    float pmax = fmaxf(max3f(b0, b1, b2), b3);
    pmax = fmaxf(pmax, __shfl_xor(pmax, 32, 64));

    if (!__all(pmax <= mrun + 8.f)){      // defer-max (T13)
      float mnew = fmaxf(mrun, pmax);
      float alp = __expf(mrun - mnew);
      mrun = mnew;
      lrun *= alp;
      #pragma unroll
      for (int r = 0; r < 16; r++){ ot0[r] *= alp; ot1[r] *= alp; }
    }

    #pragma unroll
    for (int r = 0; r < 16; r++){
      st0[r] = __expf(st0[r] - mrun);
      st1[r] = __expf(st1[r] - mrun);
    }
    float s8[8];
    #pragma unroll
    for (int r = 0; r < 8; r++)
      s8[r] = (st0[r] + st0[r+8]) + (st1[r] + st1[r+8]);
    float psum = ((s8[0]+s8[1])+(s8[2]+s8[3])) + ((s8[4]+s8[5])+(s8[6]+s8[7]));
    psum += __shfl_xor(psum, 32, 64);
    lrun += psum;

    u32 pw[16];
    #pragma unroll
    for (int g2 = 0; g2 < 4; g2++){
      pw[g2*2+0]   = cvtpk(st0[g2*4+0], st0[g2*4+1]);
      pw[g2*2+1]   = cvtpk(st0[g2*4+2], st0[g2*4+3]);
      pw[8+g2*2+0] = cvtpk(st1[g2*4+0], st1[g2*4+1]);
      pw[8+g2*2+1] = cvtpk(st1[g2*4+2], st1[g2*4+3]);
    }
    s16x8 pb[4];
    #pragma unroll
    for (int ks = 0; ks < 4; ks++){
      const int e = (ks>>1)*8 + (ks&1)*4;
      u32 w0 = pw[e+0], w1 = pw[e+1], w2 = pw[e+2], w3 = pw[e+3];
      plswap(w0, w2);
      plswap(w1, w3);
      u32x4 wv = { w0, w1, w2, w3 };
      pb[ks] = __builtin_bit_cast(s16x8, wv);
    }

    __builtin_amdgcn_s_setprio(1);
    #pragma unroll
    for (int ks = 0; ks < 4; ks++){
      s16x8 vf0 = lds16(sV, l31,      ks*32 + hi*16);
      s16x8 vf1 = lds16(sV, 32 + l31, ks*32 + hi*16);
      mfma32(ot0, vf0, pb[ks]);
      mfma32(ot1, vf1, pb[ks]);
    }
    __builtin_amdgcn_s_setprio(0);

    __syncthreads();
  }

  float* sO = reinterpret_cast<float*>(&smem[0][0][0][0]);
  float* sM = reinterpret_cast<float*>(&smem[0][0][0][0]) + 128*68;
  const int ql = gw*32 + l31;

  if (grp == 1){
    #pragma unroll
    for (int r4 = 0; r4 < 4; r4++){
      const int d0 = r4*8 + hi*4;
      #pragma unroll
      for (int j = 0; j < 4; j++){
        sO[ql*68 + d0 + j]      = ot0[r4*4+j];
        sO[ql*68 + 32 + d0 + j] = ot1[r4*4+j];
      }
    }
    if (hi == 0){ sM[ql*2+0] = mrun; sM[ql*2+1] = lrun; }
  }
  __syncthreads();
  if (grp == 0){
    const float m1 = sM[ql*2+0], l1 = sM[ql*2+1];
    const float M  = fmaxf(mrun, m1);
    const float w0 = __expf(mrun - M), w1e = __expf(m1 - M);
    const float inv = 1.0f / (lrun*w0 + l1*w1e);

    const int b = bh >> 4, h = bh & 15;
    u16* orow = AOh + ((size_t)b*SEQ + qrow) * FD + h*64;
    #pragma unroll
    for (int r4 = 0; r4 < 4; r4++){
      const int d0 = r4*8 + hi*4;
      u16x4 v0, v1;
      #pragma unroll
      for (int j = 0; j < 4; j++){
        v0[j] = f2bf((ot0[r4*4+j]*w0 + sO[ql*68 + d0 + j]*w1e) * inv);
        v1[j] = f2bf((ot1[r4*4+j]*w0 + sO[ql*68 + 32 + d0 + j]*w1e) * inv);
      }
      *reinterpret_cast<u16x4*>(orow + d0)      = v0;
      *reinterpret_cast<u16x4*>(orow + 32 + d0) = v1;
    }
  }
}

// ---------------------------------------------------------------------------
extern "C" void kernel_launch(void* const* d_in, const int* in_sizes, int n_in,
                              void* d_out, int out_size, void* d_ws, size_t ws_size,
                              hipStream_t stream)
{
  const float* q  = (const float*)d_in[0];
  const float* k  = (const float*)d_in[1];
  const float* v  = (const float*)d_in[2];
  const float* Wq = (const float*)d_in[3];
  const float* bq = (const float*)d_in[4];
  const float* Wk = (const float*)d_in[5];
  const float* bk = (const float*)d_in[6];
  const float* Wv = (const float*)d_in[7];
  const float* bv = (const float*)d_in[8];
  const float* Wo = (const float*)d_in[9];
  const float* bo = (const float*)d_in[10];
  float* out = (float*)d_out;
  (void)in_sizes; (void)n_in; (void)out_size; (void)ws_size;

  char* ws = (char*)d_ws;
  size_t off = 0;
  auto alloc = [&](size_t bytes) -> char* {
    char* p = ws + off;
    off += (bytes + 255) & ~(size_t)255;
    return p;
  };
  const size_t WB = (size_t)FD * FD * sizeof(u16);             // 2 MB
  u16* WqTh = (u16*)alloc(WB);
  u16* WkTh = (u16*)alloc(WB);
  u16* WvTh = (u16*)alloc(WB);
  u16* WoTh = (u16*)alloc(WB);
  const size_t QB = (size_t)BB * NH * SEQ * DHD * sizeof(u16); // 8 MB
  u16* Q2  = (u16*)alloc(QB);
  u16* K2  = (u16*)alloc(QB);
  u16* Vt2 = (u16*)alloc(QB);
  const size_t AB = (size_t)BB * SEQ * FD * sizeof(u16);       // 8 MB
  u16* AOh = (u16*)alloc(AB);

  wprep_all<<<dim3(16,16,4), 256, 0, stream>>>(Wq, Wk, Wv, Wo,
                                               WqTh, WkTh, WvTh, WoTh);

  qkv_gemm<<<dim3(768), 256, 0, stream>>>(q, k, v, WqTh, WkTh, WvTh,
                                          bq, bk, bv, Q2, K2, Vt2);

  attn_k<<<dim3(16,32), 512, 0, stream>>>(Q2, K2, Vt2, AOh);

  ogemm_k<<<dim3(512), 256, 0, stream>>>(AOh, WoTh, bo, out);
}

// Round 19
// 132.751 us; speedup vs baseline: 1.0453x; 1.0298x over previous
//
#include <hip/hip_runtime.h>
#include <hip/hip_bf16.h>

typedef float f32x4  __attribute__((ext_vector_type(4)));
typedef float f32x16 __attribute__((ext_vector_type(16)));
typedef short s16x8  __attribute__((ext_vector_type(8)));
typedef __bf16 bf16x8 __attribute__((ext_vector_type(8)));
typedef unsigned int u32;
typedef unsigned short u16;
typedef u16 u16x4 __attribute__((ext_vector_type(4)));
typedef u32 u32x4 __attribute__((ext_vector_type(4)));

#define DEVI static __device__ __forceinline__

constexpr int BB   = 2;
constexpr int SEQ  = 2048;
constexpr int FD   = 1024;
constexpr int NH   = 16;
constexpr int DHD  = 64;
constexpr int MROWS = BB * SEQ;

DEVI u16 f2bf(float x){
  __hip_bfloat16 h = __float2bfloat16(x);
  return __builtin_bit_cast(u16, h);
}
DEVI float bf2f(u16 u){
  return __bfloat162float(__builtin_bit_cast(__hip_bfloat16, u));
}
// HW packed f32->bf16 RNE (bit-identical to __float2bfloat16 for finite normals).
DEVI u32 cvtpk(float lo, float hi){
  u32 r;
  asm("v_cvt_pk_bf16_f32 %0, %1, %2" : "=v"(r) : "v"(lo), "v"(hi));
  return r;
}
DEVI float max3f(float a, float b, float c){
  float r;
  asm("v_max3_f32 %0, %1, %2, %3" : "=v"(r) : "v"(a), "v"(b), "v"(c));
  return r;
}

// MFMA via compiler BUILTINS (R19 experiment): same instructions as the old
// inline asm, but visible to LLVM's hazard recognizer / scheduler. Theory:
// the R7/R8/R12/R15 ~1e-2 failures were missed MFMA waitstates around opaque
// asm; builtins let the backend insert them.
DEVI void mfma_bf16(f32x4& acc, s16x8 a, s16x8 b){
  acc = __builtin_amdgcn_mfma_f32_16x16x32_bf16(
          __builtin_bit_cast(bf16x8, a), __builtin_bit_cast(bf16x8, b), acc, 0, 0, 0);
}
DEVI void mfma32(f32x16& acc, s16x8 a, s16x8 b){
  acc = __builtin_amdgcn_mfma_f32_32x32x16_bf16(
          __builtin_bit_cast(bf16x8, a), __builtin_bit_cast(bf16x8, b), acc, 0, 0, 0);
}
// v_permlane32_swap_b32 vdst, vsrc: vdst.lanes[32:63] <-> vsrc.lanes[0:31].
DEVI void plswap(u32& a, u32& b){
  asm("v_permlane32_swap_b32 %0, %1" : "+v"(a), "+v"(b));
}

#define AS1C(p) ((const __attribute__((address_space(1))) void*)(p))
#define AS3(p)  ((__attribute__((address_space(3))) void*)(p))

#define VMCNT(n)  asm volatile("s_waitcnt vmcnt(" #n ")" ::: "memory")
#define LGKMCNT0  asm volatile("s_waitcnt lgkmcnt(0)" ::: "memory")
DEVI void barrier(){ __builtin_amdgcn_s_barrier(); __builtin_amdgcn_sched_barrier(0); }

// ---------------------------------------------------------------------------
// Weight prep: W[k][n] fp32 -> WT[n][k] bf16. (Frozen.)
// ---------------------------------------------------------------------------
__global__ __launch_bounds__(256) void wprep_all(
    const float* __restrict__ W0, const float* __restrict__ W1,
    const float* __restrict__ W2, const float* __restrict__ W3,
    u16* __restrict__ T0, u16* __restrict__ T1,
    u16* __restrict__ T2, u16* __restrict__ T3)
{
  const int z = blockIdx.z;
  const float* W = z==0?W0 : z==1?W1 : z==2?W2 : W3;
  u16* Th       = z==0?T0 : z==1?T1 : z==2?T2 : T3;

  __shared__ float tile[64][65];
  const int kb = blockIdx.x * 64, nb = blockIdx.y * 64;
  const int t  = threadIdx.x;
  const int r  = t >> 2, c0 = (t & 3) * 16;

  const float* src = W + (size_t)(kb + r) * FD + nb + c0;
  #pragma unroll
  for (int i = 0; i < 16; i += 4){
    float4 v = *reinterpret_cast<const float4*>(src + i);
    tile[r][c0+i+0] = v.x; tile[r][c0+i+1] = v.y;
    tile[r][c0+i+2] = v.z; tile[r][c0+i+3] = v.w;
  }
  __syncthreads();

  s16x8 hA, hB;
  #pragma unroll
  for (int i = 0; i < 8; i++){
    hA[i] = (short)f2bf(tile[c0 + i][r]);
    hB[i] = (short)f2bf(tile[c0 + 8 + i][r]);
  }
  const size_t o = (size_t)(nb + r) * FD + kb + c0;
  *reinterpret_cast<s16x8*>(Th + o)     = hA;
  *reinterpret_cast<s16x8*>(Th + o + 8) = hB;
}

// LDS bf16 tile, 64B rows (qkv W): chunk-XOR ((row>>1)&3), 2-way free.
DEVI s16x8 ldsT(const u16* base, int row, int g){
  const char* p = reinterpret_cast<const char*>(base);
  return *reinterpret_cast<const s16x8*>(p + (row << 6) + ((g ^ ((row >> 1) & 3)) << 4));
}
// LDS bf16 tile, 128B rows (ogemm BK=64): chunk-XOR (row&7).
DEVI s16x8 lds64(const u16* base, int row, int chunk){
  const char* p = reinterpret_cast<const char*>(base);
  return *reinterpret_cast<const s16x8*>(p + (row << 7) + ((chunk ^ (row & 7)) << 4));
}

// ---------------------------------------------------------------------------
// Fused Q/K/V projections — R16-exact structure.
// fp32 A staged directly via global_load_lds, cvtpk at fragment read.
// ---------------------------------------------------------------------------
__global__ __launch_bounds__(256, 3) void qkv_gemm(
    const float* __restrict__ qp, const float* __restrict__ kp, const float* __restrict__ vp,
    const u16* __restrict__ Wq, const u16* __restrict__ Wk, const u16* __restrict__ Wv,
    const float* __restrict__ bq, const float* __restrict__ bk, const float* __restrict__ bv,
    u16* __restrict__ Q2, u16* __restrict__ K2, u16* __restrict__ Vt2)
{
  __shared__ float sAf[2][128*32];   // fp32 A tile, 128 B rows (32 KB)
  __shared__ u16   sW [2][128*32];   // bf16 W tile, 64 B rows (16 KB)

  const int bid  = blockIdx.x;
  const int xcd  = bid & 7, idx = bid >> 3;          // idx 0..95
  const int strip = xcd * 12 + (idx >> 3);           // 0..95
  const int nb   = idx & 7;
  const int z    = strip >> 5, my = strip & 31;

  const float* Ap   = z==0?qp : z==1?kp : vp;
  const u16*  Wh    = z==0?Wq : z==1?Wk : Wv;
  const float* bias = z==0?bq : z==1?bk : bv;
  u16* outp         = z==0?Q2 : z==1?K2 : Vt2;
  const float oscale = (z==0) ? 0.125f : 1.0f;
  const bool  tr     = (z==2);

  const int t    = threadIdx.x;
  const int nb0  = nb * 128, mb0 = my * 128;
  const int lane = t & 63, w = t >> 6;
  const int r16  = lane & 15, g = lane >> 4;
  const int wm   = (w >> 1) * 64, wn = (w & 1) * 64;

  const int aRow   = lane >> 3;                      // 0..7
  const int aChunk = ((lane & 7) ^ aRow) * 4;        // float offset of 16B chunk
  const int sRow   = lane >> 2;                      // 0..15
  const int sChunk = (lane & 3);

  auto stage = [&](int buf, int kb){
    #pragma unroll
    for (int i = 0; i < 4; i++){                     // A: 4 issues x 8 rows
      const int row = w*32 + i*8 + aRow;
      const float* ag = Ap + (size_t)(mb0 + row) * FD + kb + aChunk;
      __builtin_amdgcn_global_load_lds(AS1C(ag), AS3(&sAf[buf][(w*32 + i*8)*32]), 16, 0, 0);
    }
    #pragma unroll
    for (int i = 0; i < 2; i++){                     // W: 2 issues x 16 rows
      const int row = w*32 + i*16 + sRow;
      const int gch = sChunk ^ ((row >> 1) & 3);
      const u16* wg = Wh + (size_t)(nb0 + row) * FD + kb + gch*8;
      __builtin_amdgcn_global_load_lds(AS1C(wg), AS3(&sW[buf][(w*32 + i*16)*32]), 16, 0, 0);
    }
  };
  auto ldsA = [&](const float* base, int row, int gg) -> s16x8 {
    const char* p = reinterpret_cast<const char*>(base);
    const int roff = row << 7, sw = (row & 7) << 4;
    f32x4 lo = *reinterpret_cast<const f32x4*>(p + roff + ((gg*32)      ^ sw));
    f32x4 hi = *reinterpret_cast<const f32x4*>(p + roff + ((gg*32 + 16) ^ sw));
    u32 w0 = cvtpk(lo[0], lo[1]);
    u32 w1 = cvtpk(lo[2], lo[3]);
    u32 w2 = cvtpk(hi[0], hi[1]);
    u32 w3 = cvtpk(hi[2], hi[3]);
    u32x4 wv = { w0, w1, w2, w3 };
    return __builtin_bit_cast(s16x8, wv);
  };

  f32x4 acc[4][4] = {};

  stage(0, 0);
  stage(1, 32);
  VMCNT(6);            // buf0's 6 loads landed
  barrier();

  #pragma unroll 2
  for (int it = 0; it < FD/32; it++){
    const int buf = it & 1;

    s16x8 a[4], bh[4];
    #pragma unroll
    for (int i = 0; i < 4; i++)
      a[i]  = ldsA(sAf[buf], wm + i*16 + r16, g);
    #pragma unroll
    for (int j = 0; j < 4; j++)
      bh[j] = ldsT(sW[buf], wn + j*16 + r16, g);
    LGKMCNT0;          // this wave's reads of buf retired
    barrier();         // ALL waves done with buf -> safe to overwrite

    if (it + 2 < FD/32) stage(buf, (it + 2) * 32);

    __builtin_amdgcn_s_setprio(1);
    #pragma unroll
    for (int i = 0; i < 4; i++)
      #pragma unroll
      for (int j = 0; j < 4; j++)
        mfma_bf16(acc[i][j], a[i], bh[j]);
    __builtin_amdgcn_s_setprio(0);

    if (it + 2 < FD/32) { VMCNT(6); }   // wait only buf^1's loads (1 iter old)
    else                { VMCNT(0); }
    barrier();
  }

  #pragma unroll
  for (int i = 0; i < 4; i++){
    #pragma unroll
    for (int j = 0; j < 4; j++){
      const int ccol = nb0 + wn + j*16 + r16;
      const float bv = bias[ccol];
      #pragma unroll
      for (int r = 0; r < 4; r++){
        const int m = mb0 + wm + i*16 + g*4 + r;
        const float v = (acc[i][j][r] + bv) * oscale;
        const int b = m >> 11, n = m & (SEQ - 1);
        const int h = ccol >> 6, d = ccol & 63;
        const size_t o = tr ? ((size_t)(b*NH + h)*DHD + d)*SEQ + n
                            : ((size_t)(b*NH + h)*SEQ + n)*DHD + d;
        outp[o] = f2bf(v);
      }
    }
  }
}

// ---------------------------------------------------------------------------
// O-projection GEMM — BK=64 counted-vmcnt (R18-exact structure).
// ---------------------------------------------------------------------------
__global__ __launch_bounds__(256, 3) void ogemm_k(
    const u16* __restrict__ Ap, const u16* __restrict__ Wh,
    const float* __restrict__ bias, float* __restrict__ outp)
{
  __shared__ u16 sA[2][64*64];    // 16 KB
  __shared__ u16 sW[2][128*64];   // 32 KB

  const int bid  = blockIdx.x;
  const int xcd  = bid & 7, idx = bid >> 3;
  const int my   = xcd * 8 + (idx >> 3);
  const int nb   = idx & 7;

  const int t    = threadIdx.x;
  const int nb0  = nb * 128, mb0 = my * 64;
  const int lane = t & 63, w = t >> 6;
  const int r16  = lane & 15, g = lane >> 4;
  const int wm   = (w >> 1) * 32, wn = (w & 1) * 64;

  const int sRow8 = lane >> 3;           // 0..7
  const int sChk  = lane & 7;            // 0..7

  auto stage = [&](int buf, int kb){     // kb in u16 units, step 64
    #pragma unroll
    for (int i = 0; i < 2; i++){         // A: 2 issues x 8 rows
      const int row = w*16 + i*8 + sRow8;
      const int gch = sChk ^ (row & 7);
      const u16* ag = Ap + (size_t)(mb0 + row) * FD + kb + gch*8;
      __builtin_amdgcn_global_load_lds(AS1C(ag), AS3(&sA[buf][(w*16 + i*8)*64]), 16, 0, 0);
    }
    #pragma unroll
    for (int i = 0; i < 4; i++){         // W: 4 issues x 8 rows
      const int row = w*32 + i*8 + sRow8;
      const int gch = sChk ^ (row & 7);
      const u16* wg = Wh + (size_t)(nb0 + row) * FD + kb + gch*8;
      __builtin_amdgcn_global_load_lds(AS1C(wg), AS3(&sW[buf][(w*32 + i*8)*64]), 16, 0, 0);
    }
  };

  f32x4 acc[2][4] = {};

  stage(0, 0);
  stage(1, 64);
  VMCNT(6);
  barrier();

  for (int it = 0; it < FD/64; it++){    // 16 iterations
    const int buf = it & 1;

    s16x8 a0[2], a1[2], b0[4], b1[4];
    #pragma unroll
    for (int i = 0; i < 2; i++){
      a0[i] = lds64(sA[buf], wm + i*16 + r16, g);       // kk=0
      a1[i] = lds64(sA[buf], wm + i*16 + r16, 4 + g);   // kk=1
    }
    #pragma unroll
    for (int j = 0; j < 4; j++){
      b0[j] = lds64(sW[buf], wn + j*16 + r16, g);
      b1[j] = lds64(sW[buf], wn + j*16 + r16, 4 + g);
    }
    LGKMCNT0;
    barrier();

    if (it + 2 < FD/64) stage(buf, (it + 2) * 64);

    __builtin_amdgcn_s_setprio(1);
    #pragma unroll
    for (int i = 0; i < 2; i++)
      #pragma unroll
      for (int j = 0; j < 4; j++)
        mfma_bf16(acc[i][j], a0[i], b0[j]);   // == old iter 2it
    #pragma unroll
    for (int i = 0; i < 2; i++)
      #pragma unroll
      for (int j = 0; j < 4; j++)
        mfma_bf16(acc[i][j], a1[i], b1[j]);   // == old iter 2it+1
    __builtin_amdgcn_s_setprio(0);

    if (it + 2 < FD/64) { VMCNT(6); }
    else                { VMCNT(0); }
    barrier();
  }

  #pragma unroll
  for (int i = 0; i < 2; i++){
    #pragma unroll
    for (int j = 0; j < 4; j++){
      const int ccol = nb0 + wn + j*16 + r16;
      const float bv = bias[ccol];
      #pragma unroll
      for (int r = 0; r < 4; r++){
        const int m = mb0 + wm + i*16 + g*4 + r;
        outp[(size_t)m * FD + ccol] = acc[i][j][r] + bv;
      }
    }
  }
}

// ---------------------------------------------------------------------------
// Flash attention — R11-exact body (passing); only the MFMA helper impl
// changed (asm -> builtin, same instruction). Structure remains FROZEN.
// ---------------------------------------------------------------------------
__global__ __launch_bounds__(512, 4) void attn_k(
    const u16* __restrict__ Q2, const u16* __restrict__ K2, const u16* __restrict__ Vt2,
    u16* __restrict__ AOh)
{
  __shared__ u16 smem[2][2][2][64*64];

  const int bid = blockIdx.x + 16 * blockIdx.y;
  const int qt  = bid >> 5;
  const int bh  = (bid & 7) * 4 + ((bid >> 3) & 3);

  const int t = threadIdx.x, w = t >> 6, lane = t & 63;
  const int grp = w >> 2, gw = w & 3;
  const int l31 = lane & 31, hi = lane >> 5;

  const u16* Kb = K2  + (size_t)bh * SEQ * DHD;
  const u16* Vb = Vt2 + (size_t)bh * DHD * SEQ;

  const int srow8  = lane >> 3;
  const int schunk = ((lane & 7) ^ srow8) * 8;

  const int qrow = qt*128 + gw*32 + l31;
  const u16* Qrow = Q2 + ((size_t)bh * SEQ + qrow) * DHD;
  s16x8 qf[4];
  #pragma unroll
  for (int dk = 0; dk < 4; dk++)
    qf[dk] = *reinterpret_cast<const s16x8*>(Qrow + dk*16 + hi*8);

  f32x16 ot0 = {}, ot1 = {};
  float mrun = -1e30f, lrun = 0.f;

  auto stage_tile = [&](int buf, int kt){
    #pragma unroll
    for (int i = 0; i < 2; i++){
      const int row = gw*16 + i*8 + srow8;
      const u16* kg = Kb + (size_t)(kt*64 + row) * DHD + schunk;
      const u16* vg = Vb + (size_t)row * SEQ + kt*64 + schunk;
      __builtin_amdgcn_global_load_lds(AS1C(kg), AS3(&smem[0][grp][buf][(gw*16 + i*8)*64]), 16, 0, 0);
      __builtin_amdgcn_global_load_lds(AS1C(vg), AS3(&smem[1][grp][buf][(gw*16 + i*8)*64]), 16, 0, 0);
    }
  };
  auto lds16 = [](const u16* base, int row, int colbyte) -> s16x8 {
    int off = (row << 7) + colbyte;
    off ^= (row & 7) << 4;
    return *reinterpret_cast<const s16x8*>(reinterpret_cast<const char*>(base) + off);
  };

  constexpr int NIT = SEQ / 64 / 2;
  stage_tile(0, grp);
  __syncthreads();

  for (int i = 0; i < NIT; i++){
    const int buf = i & 1;
    if (i + 1 < NIT) stage_tile(buf ^ 1, 2*(i+1) + grp);
    const u16* sK = &smem[0][grp][buf][0];
    const u16* sV = &smem[1][grp][buf][0];

    f32x16 st0 = {}, st1 = {};
    __builtin_amdgcn_s_setprio(1);
    #pragma unroll
    for (int dk = 0; dk < 4; dk++){
      s16x8 kf0 = lds16(sK, l31,      dk*32 + hi*16);
      s16x8 kf1 = lds16(sK, 32 + l31, dk*32 + hi*16);
      mfma32(st0, kf0, qf[dk]);
      mfma32(st1, kf1, qf[dk]);
    }
    __builtin_amdgcn_s_setprio(0);

    float a0 = max3f(st0[0],  st0[1],  st0[2]);
    float a1 = max3f(st0[3],  st0[4],  st0[5]);
    float a2 = max3f(st0[6],  st0[7],  st0[8]);
    float a3 = max3f(st0[9],  st0[10], st0[11]);
    float a4 = max3f(st0[12], st0[13], st0[14]);
    float a5 = max3f(st1[0],  st1[1],  st1[2]);
    float a6 = max3f(st1[3],  st1[4],  st1[5]);
    float a7 = max3f(st1[6],  st1[7],  st1[8]);
    float a8 = max3f(st1[9],  st1[10], st1[11]);
    float a9 = max3f(st1[12], st1[13], st1[14]);
    float b0 = max3f(a0, a1, a2);
    float b1 = max3f(a3, a4, a5);
    float b2 = max3f(a6, a7, a8);
    float b3 = max3f(a9, st0[15], st1[15]);
    float pmax = fmaxf(max3f(b0, b1, b2), b3);
    pmax = fmaxf(pmax, __shfl_xor(pmax, 32, 64));

    if (!__all(pmax <= mrun + 8.f)){      // defer-max (T13)
      float mnew = fmaxf(mrun, pmax);
      float alp = __expf(mrun - mnew);
      mrun = mnew;
      lrun *= alp;
      #pragma unroll
      for (int r = 0; r < 16; r++){ ot0[r] *= alp; ot1[r] *= alp; }
    }

    #pragma unroll
    for (int r = 0; r < 16; r++){
      st0[r] = __expf(st0[r] - mrun);
      st1[r] = __expf(st1[r] - mrun);
    }
    float s8[8];
    #pragma unroll
    for (int r = 0; r < 8; r++)
      s8[r] = (st0[r] + st0[r+8]) + (st1[r] + st1[r+8]);
    float psum = ((s8[0]+s8[1])+(s8[2]+s8[3])) + ((s8[4]+s8[5])+(s8[6]+s8[7]));
    psum += __shfl_xor(psum, 32, 64);
    lrun += psum;

    u32 pw[16];
    #pragma unroll
    for (int g2 = 0; g2 < 4; g2++){
      pw[g2*2+0]   = cvtpk(st0[g2*4+0], st0[g2*4+1]);
      pw[g2*2+1]   = cvtpk(st0[g2*4+2], st0[g2*4+3]);
      pw[8+g2*2+0] = cvtpk(st1[g2*4+0], st1[g2*4+1]);
      pw[8+g2*2+1] = cvtpk(st1[g2*4+2], st1[g2*4+3]);
    }
    s16x8 pb[4];
    #pragma unroll
    for (int ks = 0; ks < 4; ks++){
      const int e = (ks>>1)*8 + (ks&1)*4;
      u32 w0 = pw[e+0], w1 = pw[e+1], w2 = pw[e+2], w3 = pw[e+3];
      plswap(w0, w2);
      plswap(w1, w3);
      u32x4 wv = { w0, w1, w2, w3 };
      pb[ks] = __builtin_bit_cast(s16x8, wv);
    }

    __builtin_amdgcn_s_setprio(1);
    #pragma unroll
    for (int ks = 0; ks < 4; ks++){
      s16x8 vf0 = lds16(sV, l31,      ks*32 + hi*16);
      s16x8 vf1 = lds16(sV, 32 + l31, ks*32 + hi*16);
      mfma32(ot0, vf0, pb[ks]);
      mfma32(ot1, vf1, pb[ks]);
    }
    __builtin_amdgcn_s_setprio(0);

    __syncthreads();
  }

  float* sO = reinterpret_cast<float*>(&smem[0][0][0][0]);
  float* sM = reinterpret_cast<float*>(&smem[0][0][0][0]) + 128*68;
  const int ql = gw*32 + l31;

  if (grp == 1){
    #pragma unroll
    for (int r4 = 0; r4 < 4; r4++){
      const int d0 = r4*8 + hi*4;
      #pragma unroll
      for (int j = 0; j < 4; j++){
        sO[ql*68 + d0 + j]      = ot0[r4*4+j];
        sO[ql*68 + 32 + d0 + j] = ot1[r4*4+j];
      }
    }
    if (hi == 0){ sM[ql*2+0] = mrun; sM[ql*2+1] = lrun; }
  }
  __syncthreads();
  if (grp == 0){
    const float m1 = sM[ql*2+0], l1 = sM[ql*2+1];
    const float M  = fmaxf(mrun, m1);
    const float w0 = __expf(mrun - M), w1e = __expf(m1 - M);
    const float inv = 1.0f / (lrun*w0 + l1*w1e);

    const int b = bh >> 4, h = bh & 15;
    u16* orow = AOh + ((size_t)b*SEQ + qrow) * FD + h*64;
    #pragma unroll
    for (int r4 = 0; r4 < 4; r4++){
      const int d0 = r4*8 + hi*4;
      u16x4 v0, v1;
      #pragma unroll
      for (int j = 0; j < 4; j++){
        v0[j] = f2bf((ot0[r4*4+j]*w0 + sO[ql*68 + d0 + j]*w1e) * inv);
        v1[j] = f2bf((ot1[r4*4+j]*w0 + sO[ql*68 + 32 + d0 + j]*w1e) * inv);
      }
      *reinterpret_cast<u16x4*>(orow + d0)      = v0;
      *reinterpret_cast<u16x4*>(orow + 32 + d0) = v1;
    }
  }
}

// ---------------------------------------------------------------------------
extern "C" void kernel_launch(void* const* d_in, const int* in_sizes, int n_in,
                              void* d_out, int out_size, void* d_ws, size_t ws_size,
                              hipStream_t stream)
{
  const float* q  = (const float*)d_in[0];
  const float* k  = (const float*)d_in[1];
  const float* v  = (const float*)d_in[2];
  const float* Wq = (const float*)d_in[3];
  const float* bq = (const float*)d_in[4];
  const float* Wk = (const float*)d_in[5];
  const float* bk = (const float*)d_in[6];
  const float* Wv = (const float*)d_in[7];
  const float* bv = (const float*)d_in[8];
  const float* Wo = (const float*)d_in[9];
  const float* bo = (const float*)d_in[10];
  float* out = (float*)d_out;
  (void)in_sizes; (void)n_in; (void)out_size; (void)ws_size;

  char* ws = (char*)d_ws;
  size_t off = 0;
  auto alloc = [&](size_t bytes) -> char* {
    char* p = ws + off;
    off += (bytes + 255) & ~(size_t)255;
    return p;
  };
  const size_t WB = (size_t)FD * FD * sizeof(u16);             // 2 MB
  u16* WqTh = (u16*)alloc(WB);
  u16* WkTh = (u16*)alloc(WB);
  u16* WvTh = (u16*)alloc(WB);
  u16* WoTh = (u16*)alloc(WB);
  const size_t QB = (size_t)BB * NH * SEQ * DHD * sizeof(u16); // 8 MB
  u16* Q2  = (u16*)alloc(QB);
  u16* K2  = (u16*)alloc(QB);
  u16* Vt2 = (u16*)alloc(QB);
  const size_t AB = (size_t)BB * SEQ * FD * sizeof(u16);       // 8 MB
  u16* AOh = (u16*)alloc(AB);

  wprep_all<<<dim3(16,16,4), 256, 0, stream>>>(Wq, Wk, Wv, Wo,
                                               WqTh, WkTh, WvTh, WoTh);

  qkv_gemm<<<dim3(768), 256, 0, stream>>>(q, k, v, WqTh, WkTh, WvTh,
                                          bq, bk, bv, Q2, K2, Vt2);

  attn_k<<<dim3(16,32), 512, 0, stream>>>(Q2, K2, Vt2, AOh);

  ogemm_k<<<dim3(512), 256, 0, stream>>>(AOh, WoTh, bo, out);
}